// Round 5
// baseline (408.812 us; speedup 1.0000x reference)
//
#include <hip/hip_runtime.h>
#include <math.h>

#define NQC   2048
#define NKVC  2048
#define DIMC  256
#define SCALEF 0.17677669529663687f   // 1/sqrt(32), folded into Q weights in prep_w

typedef short bfrag __attribute__((ext_vector_type(8)));   // 8 bf16 = 4 VGPRs
typedef float ffrag __attribute__((ext_vector_type(4)));   // MFMA C/D
typedef unsigned short us8 __attribute__((ext_vector_type(8)));

__device__ __forceinline__ float gelu_exact(float x) {
    return 0.5f * x * (1.0f + erff(x * 0.70710678118654752f));
}
__device__ __forceinline__ unsigned short f2bf(float f) {
    union { float f; unsigned u; } v; v.f = f;
    unsigned r = v.u + 0x7FFFu + ((v.u >> 16) & 1u);   // RNE
    return (unsigned short)(r >> 16);
}
__device__ __forceinline__ float bf2f(unsigned short u) {
    union { unsigned u; float f; } v; v.u = ((unsigned)u) << 16;
    return v.f;
}

// ---------------- weight prep: transpose + cast + concat + knn-diff + Q-scale ----------------
// dst regions (bf16, row-major [N][K]):
//  WT1    [1280][256] @0       : qkv (Q cols pre-scaled) | knn_top | knn_diff
//  WTproj [256][256]  @327680
//  WTmerge[256][512]  @393216
//  WT2    [512][256]  @524288  : ca_q (pre-scaled) | knnx_diff
//  WT3    [768][256]  @655360  : ca_kv(K,V) | knnx_top
//  WTprojx[256][256]  @851968
//  WTmergex[256][512] @917504
//  WTfc1  [1024][256] @1048576
//  WTfc2  [256][1024] @1310720   (total 1572864 ushorts)
__global__ __launch_bounds__(256) void prep_w(
    const float* __restrict__ qkv, const float* __restrict__ knn,
    const float* __restrict__ proj, const float* __restrict__ merge,
    const float* __restrict__ caq, const float* __restrict__ knnx,
    const float* __restrict__ cakv, const float* __restrict__ projx,
    const float* __restrict__ mergex, const float* __restrict__ fc1,
    const float* __restrict__ fc2, unsigned short* __restrict__ dst)
{
    int e = (blockIdx.x * 256 + threadIdx.x) * 4;
    float v[4];
    float scale = 1.0f;
    if (e < 327680) {
        int n = e >> 8, k = e & 255;
        if (n < 768) {
            const float* s = qkv + (size_t)k * 768 + n;
            #pragma unroll
            for (int i = 0; i < 4; ++i) v[i] = s[(size_t)i * 768];
            if (n < 256) scale = SCALEF;            // Q columns: fold attention scale
        } else if (n < 1024) {
            const float* s = knn + (size_t)k * 256 + (n - 768);
            #pragma unroll
            for (int i = 0; i < 4; ++i) v[i] = s[(size_t)i * 256];
        } else {
            const float* s = knn + (size_t)k * 256 + (n - 1024);
            #pragma unroll
            for (int i = 0; i < 4; ++i) v[i] = s[65536 + (size_t)i * 256] - s[(size_t)i * 256];
        }
    } else if (e < 393216) {
        int l = e - 327680, n = l >> 8, k = l & 255;
        const float* s = proj + (size_t)k * 256 + n;
        #pragma unroll
        for (int i = 0; i < 4; ++i) v[i] = s[(size_t)i * 256];
    } else if (e < 524288) {
        int l = e - 393216, n = l >> 9, k = l & 511;
        const float* s = merge + (size_t)k * 256 + n;
        #pragma unroll
        for (int i = 0; i < 4; ++i) v[i] = s[(size_t)i * 256];
    } else if (e < 655360) {
        int l = e - 524288, n = l >> 8, k = l & 255;
        if (n < 256) {
            const float* s = caq + (size_t)k * 256 + n;
            #pragma unroll
            for (int i = 0; i < 4; ++i) v[i] = s[(size_t)i * 256];
            scale = SCALEF;                         // ca_q: fold attention scale
        } else {
            const float* s = knnx + (size_t)k * 256 + (n - 256);
            #pragma unroll
            for (int i = 0; i < 4; ++i) v[i] = s[65536 + (size_t)i * 256] - s[(size_t)i * 256];
        }
    } else if (e < 851968) {
        int l = e - 655360, n = l >> 8, k = l & 255;
        if (n < 512) {
            const float* s = cakv + (size_t)k * 512 + n;
            #pragma unroll
            for (int i = 0; i < 4; ++i) v[i] = s[(size_t)i * 512];
        } else {
            const float* s = knnx + (size_t)k * 256 + (n - 512);
            #pragma unroll
            for (int i = 0; i < 4; ++i) v[i] = s[(size_t)i * 256];
        }
    } else if (e < 917504) {
        int l = e - 851968, n = l >> 8, k = l & 255;
        const float* s = projx + (size_t)k * 256 + n;
        #pragma unroll
        for (int i = 0; i < 4; ++i) v[i] = s[(size_t)i * 256];
    } else if (e < 1048576) {
        int l = e - 917504, n = l >> 9, k = l & 511;
        const float* s = mergex + (size_t)k * 256 + n;
        #pragma unroll
        for (int i = 0; i < 4; ++i) v[i] = s[(size_t)i * 256];
    } else if (e < 1310720) {
        int l = e - 1048576, n = l >> 8, k = l & 255;
        const float* s = fc1 + (size_t)k * 1024 + n;
        #pragma unroll
        for (int i = 0; i < 4; ++i) v[i] = s[(size_t)i * 1024];
    } else {
        int l = e - 1310720, n = l >> 10, k = l & 1023;
        const float* s = fc2 + (size_t)k * 256 + n;
        #pragma unroll
        for (int i = 0; i < 4; ++i) v[i] = s[(size_t)i * 256];
    }
    ushort4 o;
    o.x = f2bf(v[0] * scale); o.y = f2bf(v[1] * scale);
    o.z = f2bf(v[2] * scale); o.w = f2bf(v[3] * scale);
    *(ushort4*)(dst + e) = o;
}

// ---------------- bf16 MFMA GEMM, 64x64 tile, BK=64 (bf16 A input) ----------------
template<int ACT, int RESID, int OUTBF>
__global__ __launch_bounds__(256) void gemm64(
    const unsigned short* __restrict__ A, int lda,
    const unsigned short* __restrict__ Wt,
    const float* __restrict__ bias,
    const float* __restrict__ resid, int ldr,
    void* __restrict__ Cp, int ldc, int Kc)
{
    __shared__ unsigned short Alds[64][72];
    __shared__ unsigned short Wlds[64][72];
    const int tid = threadIdx.x;
    const int wid = tid >> 6, lane = tid & 63;
    const int lm = lane & 15, quad = lane >> 4;
    const int wr = wid >> 1, wc = wid & 1;
    const int row0 = blockIdx.y * 64, col0 = blockIdx.x * 64;
    const int ar = tid >> 2, ac = (tid & 3) * 16;
    const unsigned short* Ag = A  + (size_t)(row0 + ar) * lda + ac;
    const unsigned short* Wg = Wt + (size_t)(col0 + ar) * Kc  + ac;

    us8 a0 = *(const us8*)Ag;
    us8 a1 = *(const us8*)(Ag + 8);
    us8 w0 = *(const us8*)Wg;
    us8 w1 = *(const us8*)(Wg + 8);

    ffrag acc[2][2];
    #pragma unroll
    for (int mi = 0; mi < 2; ++mi)
        #pragma unroll
        for (int ni = 0; ni < 2; ++ni)
            acc[mi][ni] = (ffrag){0.f, 0.f, 0.f, 0.f};

    for (int k0 = 0;;) {
        __syncthreads();
        *(us8*)&Alds[ar][ac]   = a0;
        *(us8*)&Alds[ar][ac+8] = a1;
        *(us8*)&Wlds[ar][ac]   = w0;
        *(us8*)&Wlds[ar][ac+8] = w1;
        __syncthreads();
        k0 += 64;
        if (k0 < Kc) {
            a0 = *(const us8*)(Ag + k0);
            a1 = *(const us8*)(Ag + k0 + 8);
            w0 = *(const us8*)(Wg + k0);
            w1 = *(const us8*)(Wg + k0 + 8);
        }
        #pragma unroll
        for (int kc = 0; kc < 2; ++kc) {
            bfrag af[2], bw[2];
            #pragma unroll
            for (int mi = 0; mi < 2; ++mi)
                af[mi] = *(const bfrag*)&Alds[wr*32 + mi*16 + lm][kc*32 + quad*8];
            #pragma unroll
            for (int ni = 0; ni < 2; ++ni)
                bw[ni] = *(const bfrag*)&Wlds[wc*32 + ni*16 + lm][kc*32 + quad*8];
            #pragma unroll
            for (int mi = 0; mi < 2; ++mi)
                #pragma unroll
                for (int ni = 0; ni < 2; ++ni)
                    acc[mi][ni] = __builtin_amdgcn_mfma_f32_16x16x32_bf16(
                        af[mi], bw[ni], acc[mi][ni], 0, 0, 0);
        }
        if (k0 >= Kc) break;
    }
    #pragma unroll
    for (int mi = 0; mi < 2; ++mi) {
        #pragma unroll
        for (int ni = 0; ni < 2; ++ni) {
            int gr = row0 + wr*32 + mi*16 + quad*4;
            int gc = col0 + wc*32 + ni*16 + lm;
            float bv = bias ? bias[gc] : 0.f;
            #pragma unroll
            for (int r = 0; r < 4; ++r) {
                float o = acc[mi][ni][r] + bv;
                if (ACT == 1) o = gelu_exact(o);
                if (RESID) o += resid[(size_t)(gr + r) * ldr + gc];
                if (OUTBF) ((unsigned short*)Cp)[(size_t)(gr + r) * ldc + gc] = f2bf(o);
                else       ((float*)Cp)[(size_t)(gr + r) * ldc + gc] = o;
            }
        }
    }
}

// ---------------- fused LayerNorm + bf16 MFMA GEMM (Kc=256, fp32 A) ----------------
// LN(x)*g+b computed in-block (4 threads/row, 2-shuffle stats), normalized
// A-panel (64x256 bf16) held in LDS for the whole K-loop; only W tiles cycle.
template<int ACT>
__global__ __launch_bounds__(256) void gemm64_ln(
    const float* __restrict__ X,
    const float* __restrict__ g, const float* __restrict__ b,
    const unsigned short* __restrict__ Wt,
    const float* __restrict__ bias,
    unsigned short* __restrict__ C, int ldc)
{
    __shared__ unsigned short Alds[64][264];   // stride 264: 4-bank row skew
    __shared__ unsigned short Wlds[64][72];
    const int tid = threadIdx.x;
    const int wid = tid >> 6, lane = tid & 63;
    const int lm = lane & 15, quad = lane >> 4;
    const int wr = wid >> 1, wc = wid & 1;
    const int row0 = blockIdx.y * 64, col0 = blockIdx.x * 64;

    // --- LN: 4 threads per row, 64 cols each ---
    const int rr = tid >> 2, c0 = (tid & 3) * 64;
    const float* xp = X + (size_t)(row0 + rr) * 256 + c0;
    float s = 0.f, sq = 0.f;
    #pragma unroll
    for (int i = 0; i < 16; ++i) {
        float4 v = *(const float4*)(xp + i * 4);
        s  += (v.x + v.y) + (v.z + v.w);
        sq += (v.x*v.x + v.y*v.y) + (v.z*v.z + v.w*v.w);
    }
    s  += __shfl_xor(s, 1);  sq += __shfl_xor(sq, 1);
    s  += __shfl_xor(s, 2);  sq += __shfl_xor(sq, 2);
    float mean = s * (1.0f/256.0f);
    float inv  = rsqrtf(sq * (1.0f/256.0f) - mean*mean + 1e-5f);
    #pragma unroll
    for (int j = 0; j < 8; ++j) {
        float4 v0 = *(const float4*)(xp + j*8);
        float4 v1 = *(const float4*)(xp + j*8 + 4);
        float4 g0 = *(const float4*)(g + c0 + j*8);
        float4 g1 = *(const float4*)(g + c0 + j*8 + 4);
        float4 b0 = *(const float4*)(b + c0 + j*8);
        float4 b1 = *(const float4*)(b + c0 + j*8 + 4);
        us8 w;
        w[0] = f2bf((v0.x - mean) * inv * g0.x + b0.x);
        w[1] = f2bf((v0.y - mean) * inv * g0.y + b0.y);
        w[2] = f2bf((v0.z - mean) * inv * g0.z + b0.z);
        w[3] = f2bf((v0.w - mean) * inv * g0.w + b0.w);
        w[4] = f2bf((v1.x - mean) * inv * g1.x + b1.x);
        w[5] = f2bf((v1.y - mean) * inv * g1.y + b1.y);
        w[6] = f2bf((v1.z - mean) * inv * g1.z + b1.z);
        w[7] = f2bf((v1.w - mean) * inv * g1.w + b1.w);
        *(us8*)&Alds[rr][c0 + j*8] = w;
    }

    // --- K-loop: stage W tiles; A-panel stays resident ---
    const int ar = tid >> 2, ac = (tid & 3) * 16;
    const unsigned short* Wg = Wt + (size_t)(col0 + ar) * 256 + ac;
    us8 w0 = *(const us8*)Wg;
    us8 w1 = *(const us8*)(Wg + 8);

    ffrag acc[2][2];
    #pragma unroll
    for (int mi = 0; mi < 2; ++mi)
        #pragma unroll
        for (int ni = 0; ni < 2; ++ni)
            acc[mi][ni] = (ffrag){0.f, 0.f, 0.f, 0.f};

    #pragma unroll
    for (int k0 = 0; k0 < 256; k0 += 64) {
        __syncthreads();
        *(us8*)&Wlds[ar][ac]   = w0;
        *(us8*)&Wlds[ar][ac+8] = w1;
        __syncthreads();
        if (k0 + 64 < 256) {
            w0 = *(const us8*)(Wg + k0 + 64);
            w1 = *(const us8*)(Wg + k0 + 72);
        }
        #pragma unroll
        for (int kc = 0; kc < 2; ++kc) {
            bfrag af[2], bw[2];
            #pragma unroll
            for (int mi = 0; mi < 2; ++mi)
                af[mi] = *(const bfrag*)&Alds[wr*32 + mi*16 + lm][k0 + kc*32 + quad*8];
            #pragma unroll
            for (int ni = 0; ni < 2; ++ni)
                bw[ni] = *(const bfrag*)&Wlds[wc*32 + ni*16 + lm][kc*32 + quad*8];
            #pragma unroll
            for (int mi = 0; mi < 2; ++mi)
                #pragma unroll
                for (int ni = 0; ni < 2; ++ni)
                    acc[mi][ni] = __builtin_amdgcn_mfma_f32_16x16x32_bf16(
                        af[mi], bw[ni], acc[mi][ni], 0, 0, 0);
        }
    }
    #pragma unroll
    for (int mi = 0; mi < 2; ++mi) {
        #pragma unroll
        for (int ni = 0; ni < 2; ++ni) {
            int gr = row0 + wr*32 + mi*16 + quad*4;
            int gc = col0 + wc*32 + ni*16 + lm;
            float bv = bias ? bias[gc] : 0.f;
            #pragma unroll
            for (int r = 0; r < 4; ++r) {
                float o = acc[mi][ni][r] + bv;
                if (ACT == 1) o = gelu_exact(o);
                C[(size_t)(gr + r) * ldc + gc] = f2bf(o);
            }
        }
    }
}

// ---------------- bf16 MFMA flash attention, KV-split, fixed-max softmax ----------------
// grid (NQ/64, 8, B*2): z = b*2 + chunk; each block: 64 queries x 1024 keys.
// Fixed-max partials are exactly additive: Opart/lpart summed in attn_comb.
__global__ __launch_bounds__(256) void attn_part(
    const unsigned short* __restrict__ Qp, int ldq,
    const unsigned short* __restrict__ Kp, int ldk,
    const unsigned short* __restrict__ Vp, int ldv,
    float* __restrict__ Op, float* __restrict__ Lp)
{
    __shared__ unsigned short Klds[64][40];
    __shared__ unsigned short Vt[32][72];
    __shared__ unsigned short Plds[4][16][72];
    int zc = blockIdx.z, bb = zc >> 1, ck = zc & 1;
    int h = blockIdx.y;
    int hoff = h * 32;
    int tid = threadIdx.x, wid = tid >> 6, lane = tid & 63;
    int lm = lane & 15, quad = lane >> 4;
    size_t qbase  = (size_t)bb * NQC;
    size_t kvbase = (size_t)bb * NKVC;
    int q0 = blockIdx.x * 64 + wid * 16;

    bfrag aq = *(const bfrag*)(Qp + (qbase + q0 + lm) * (size_t)ldq + hoff + quad * 8);

    float l_r[4] = {0.f, 0.f, 0.f, 0.f};
    ffrag oacc[2];
    oacc[0] = (ffrag){0.f, 0.f, 0.f, 0.f};
    oacc[1] = (ffrag){0.f, 0.f, 0.f, 0.f};

    const int kkey = tid >> 2, kd0 = (tid & 3) * 8;
    const int vkey = tid & 63, vd0 = (tid >> 6) * 8;
    const unsigned short* kg0 = Kp + (kvbase + kkey) * (size_t)ldk + hoff + kd0;
    const unsigned short* vg0 = Vp + (kvbase + vkey) * (size_t)ldv + hoff + vd0;

    for (int kt = ck * 16; kt < ck * 16 + 16; ++kt) {
        us8 kv = *(const us8*)(kg0 + (size_t)kt * 64 * ldk);
        us8 vv = *(const us8*)(vg0 + (size_t)kt * 64 * ldv);
        __syncthreads();
        *(us8*)&Klds[kkey][kd0] = kv;
        #pragma unroll
        for (int i = 0; i < 8; ++i) Vt[vd0 + i][vkey] = vv[i];
        __syncthreads();

        ffrag sacc[4];
        #pragma unroll
        for (int t = 0; t < 4; ++t) {
            bfrag bk = *(const bfrag*)&Klds[t*16 + lm][quad * 8];
            sacc[t] = __builtin_amdgcn_mfma_f32_16x16x32_bf16(
                aq, bk, (ffrag){0.f,0.f,0.f,0.f}, 0, 0, 0);
        }

        #pragma unroll
        for (int r = 0; r < 4; ++r) {
            float p0 = __expf(sacc[0][r]), p1 = __expf(sacc[1][r]);
            float p2 = __expf(sacc[2][r]), p3 = __expf(sacc[3][r]);
            l_r[r] += (p0 + p1) + (p2 + p3);
            int row = quad * 4 + r;
            Plds[wid][row][lm +  0] = f2bf(p0);
            Plds[wid][row][lm + 16] = f2bf(p1);
            Plds[wid][row][lm + 32] = f2bf(p2);
            Plds[wid][row][lm + 48] = f2bf(p3);
        }
        asm volatile("s_waitcnt lgkmcnt(0)" ::: "memory");  // wave-private P RAW

        #pragma unroll
        for (int kc = 0; kc < 2; ++kc) {
            bfrag ap = *(const bfrag*)&Plds[wid][lm][kc*32 + quad*8];
            #pragma unroll
            for (int nt = 0; nt < 2; ++nt) {
                bfrag bv = *(const bfrag*)&Vt[nt*16 + lm][kc*32 + quad*8];
                oacc[nt] = __builtin_amdgcn_mfma_f32_16x16x32_bf16(
                    ap, bv, oacc[nt], 0, 0, 0);
            }
        }
    }
    // partial O (fp32) + partial l; division deferred to attn_comb
    #pragma unroll
    for (int nt = 0; nt < 2; ++nt)
        #pragma unroll
        for (int r = 0; r < 4; ++r)
            Op[((size_t)ck * 4096 + qbase + q0 + quad*4 + r) * 256 + hoff + nt*16 + lm]
                = oacc[nt][r];
    #pragma unroll
    for (int r = 0; r < 4; ++r) {
        float l = l_r[r];
        l += __shfl_xor(l, 1);
        l += __shfl_xor(l, 2);
        l += __shfl_xor(l, 4);
        l += __shfl_xor(l, 8);
        if (lm == 0)
            Lp[((size_t)ck * 4096 + qbase + q0 + quad*4 + r) * 8 + h] = l;
    }
}

// ---------------- combine KV-split partials: (O0+O1)/(l0+l1) -> bf16 ----------------
__global__ __launch_bounds__(256) void attn_comb(
    const float* __restrict__ Op, const float* __restrict__ Lp,
    unsigned short* __restrict__ dst)
{
    int wid = threadIdx.x >> 6, lane = threadIdx.x & 63;
    int row = blockIdx.x * 4 + wid;
    int c = lane * 4, h = c >> 5;
    float4 o0 = *(const float4*)(Op + (size_t)row * 256 + c);
    float4 o1 = *(const float4*)(Op + (size_t)(4096 + row) * 256 + c);
    float inv = 1.0f / (Lp[(size_t)row * 8 + h] + Lp[(size_t)(4096 + row) * 8 + h]);
    ushort4 o;
    o.x = f2bf((o0.x + o1.x) * inv);
    o.y = f2bf((o0.y + o1.y) * inv);
    o.z = f2bf((o0.z + o1.z) * inv);
    o.w = f2bf((o0.w + o1.w) * inv);
    *(ushort4*)(dst + (size_t)row * 256 + c) = o;
}

// ---------------- KNN gather + leaky_relu + max over K=8 (bf16 io) ----------------
__global__ __launch_bounds__(256) void gathermax_b(
    const unsigned short* __restrict__ P, int ldp,
    const unsigned short* __restrict__ Base, int ldb,
    const float* __restrict__ bias, const int* __restrict__ idx,
    unsigned short* __restrict__ out, int ldo)
{
    int wid = threadIdx.x >> 6, lane = threadIdx.x & 63;
    int q = blockIdx.x * 4 + wid;
    int b = q >> 11;
    int c = lane * 4;
    ushort4 bu = *(const ushort4*)(Base + (size_t)q * ldb + c);
    float4 bi = *(const float4*)(bias + c);
    float bsx = bf2f(bu.x) + bi.x, bsy = bf2f(bu.y) + bi.y;
    float bsz = bf2f(bu.z) + bi.z, bsw = bf2f(bu.w) + bi.w;
    float4 acc = make_float4(-3e38f, -3e38f, -3e38f, -3e38f);
    const int* ip = idx + (size_t)q * 8;
    #pragma unroll
    for (int k = 0; k < 8; ++k) {
        int j = ip[k];
        ushort4 pu = *(const ushort4*)(P + ((size_t)(b * NKVC + j)) * ldp + c);
        float t;
        t = bsx + bf2f(pu.x); t = t > 0.f ? t : 0.2f * t; acc.x = fmaxf(acc.x, t);
        t = bsy + bf2f(pu.y); t = t > 0.f ? t : 0.2f * t; acc.y = fmaxf(acc.y, t);
        t = bsz + bf2f(pu.z); t = t > 0.f ? t : 0.2f * t; acc.z = fmaxf(acc.z, t);
        t = bsw + bf2f(pu.w); t = t > 0.f ? t : 0.2f * t; acc.w = fmaxf(acc.w, t);
    }
    ushort4 o;
    o.x = f2bf(acc.x); o.y = f2bf(acc.y); o.z = f2bf(acc.z); o.w = f2bf(acc.w);
    *(ushort4*)(out + (size_t)q * ldo + c) = o;
}

extern "C" void kernel_launch(void* const* d_in, const int* in_sizes, int n_in,
                              void* d_out, int out_size, void* d_ws, size_t ws_size,
                              hipStream_t stream) {
    const float* q_in   = (const float*)d_in[0];
    const float* v_in   = (const float*)d_in[1];
    const int*   idx_s  = (const int*)d_in[4];
    const int*   idx_x  = (const int*)d_in[5];
    const float* n1g = (const float*)d_in[6],  *n1b = (const float*)d_in[7];
    const float* nqg = (const float*)d_in[8],  *nqb = (const float*)d_in[9];
    const float* nvg = (const float*)d_in[10], *nvb = (const float*)d_in[11];
    const float* n2g = (const float*)d_in[12], *n2b = (const float*)d_in[13];
    const float* sa_qkv_w  = (const float*)d_in[14];
    const float* sa_proj_w = (const float*)d_in[15];
    const float* sa_proj_b = (const float*)d_in[16];
    const float* ca_q_w    = (const float*)d_in[17];
    const float* ca_kv_w   = (const float*)d_in[18];
    const float* ca_proj_w = (const float*)d_in[19];
    const float* ca_proj_b = (const float*)d_in[20];
    const float* fc1_w = (const float*)d_in[21], *fc1_b = (const float*)d_in[22];
    const float* fc2_w = (const float*)d_in[23], *fc2_b = (const float*)d_in[24];
    const float* knn_w   = (const float*)d_in[25], *knn_b   = (const float*)d_in[26];
    const float* merge_w = (const float*)d_in[27], *merge_b = (const float*)d_in[28];
    const float* knnx_w  = (const float*)d_in[29], *knnx_b  = (const float*)d_in[30];
    const float* mergex_w = (const float*)d_in[31], *mergex_b = (const float*)d_in[32];
    float* out = (float*)d_out;

    unsigned short* A1      = (unsigned short*)d_ws;           // 4096x1280 bf16
    unsigned short* A2      = A1;                              // 4096x512 (stage2 overlay)
    unsigned short* A3      = A1 + (size_t)4096 * 512;         // 4096x768 (stage2 overlay)
    unsigned short* Hb      = A1;                              // 4096x1024 (stage3 overlay)
    unsigned short* attnraw = A1 + (size_t)4096 * 1280;        // 4096x256
    unsigned short* CC      = attnraw + (size_t)4096 * 256;    // 4096x512 concat
    unsigned short* WT      = CC + (size_t)4096 * 512;         // weights, 1572864 us
    unsigned short* WT1     = WT;
    unsigned short* WTproj  = WT + 327680;
    unsigned short* WTmerge = WT + 393216;
    unsigned short* WT2     = WT + 524288;
    unsigned short* WT3     = WT + 655360;
    unsigned short* WTprojx = WT + 851968;
    unsigned short* WTmergex= WT + 917504;
    unsigned short* WTfc1   = WT + 1048576;
    unsigned short* WTfc2   = WT + 1310720;
    float* Opart = (float*)(WT + 1572864);                     // [2][4096][256] f32
    float* Lpart = Opart + (size_t)2 * 4096 * 256;             // [2][4096][8]  f32

    dim3 blk(256);
    dim3 gAttn(NQC / 64, 8, 4);   // z = b*2 + kv-chunk

    prep_w<<<dim3(1536), blk, 0, stream>>>(sa_qkv_w, knn_w, sa_proj_w, merge_w,
        ca_q_w, knnx_w, ca_kv_w, ca_proj_w, mergex_w, fc1_w, fc2_w, WT);

    // ---- stage 1 ----
    gemm64_ln<0><<<dim3(20,64), blk, 0, stream>>>(q_in, n1g, n1b, WT1,
        nullptr, A1, 1280);                                                         // LN+[qkv|P|Base]
    attn_part<<<gAttn, blk, 0, stream>>>(A1, 1280, A1+256, 1280, A1+512, 1280,
        Opart, Lpart);
    attn_comb<<<dim3(1024), blk, 0, stream>>>(Opart, Lpart, attnraw);
    gathermax_b<<<dim3(1024), blk, 0, stream>>>(A1+768, 1280, A1+1024, 1280,
        knn_b, idx_s, CC+256, 512);                                                 // knn_out
    gemm64<0,0,1><<<dim3(4,64), blk, 0, stream>>>(attnraw, 256, WTproj,
        sa_proj_b, nullptr, 0, CC, 512, 256);                                       // sa_out
    gemm64<0,1,0><<<dim3(4,64), blk, 0, stream>>>(CC, 512, WTmerge,
        merge_b, q_in, 256, out, 256, 512);                                         // q = q + merge

    // ---- stage 2 ----
    gemm64_ln<0><<<dim3(8,64), blk, 0, stream>>>(out, nqg, nqb, WT2,
        nullptr, A2, 512);                                                          // LN+[ca_q|Base_x]
    gemm64_ln<0><<<dim3(12,64), blk, 0, stream>>>(v_in, nvg, nvb, WT3,
        nullptr, A3, 768);                                                          // LN+[ca_k|ca_v|P_x]
    attn_part<<<gAttn, blk, 0, stream>>>(A2, 512, A3, 768, A3+256, 768,
        Opart, Lpart);
    attn_comb<<<dim3(1024), blk, 0, stream>>>(Opart, Lpart, attnraw);
    gathermax_b<<<dim3(1024), blk, 0, stream>>>(A3+512, 768, A2+256, 512,
        knnx_b, idx_x, CC+256, 512);                                                // knnx_out
    gemm64<0,0,1><<<dim3(4,64), blk, 0, stream>>>(attnraw, 256, WTprojx,
        ca_proj_b, nullptr, 0, CC, 512, 256);                                       // ca_out
    gemm64<0,1,0><<<dim3(4,64), blk, 0, stream>>>(CC, 512, WTmergex,
        mergex_b, out, 256, out, 256, 512);                                         // q = q + mergex

    // ---- stage 3 ----
    gemm64_ln<1><<<dim3(16,64), blk, 0, stream>>>(out, n2g, n2b, WTfc1,
        fc1_b, Hb, 1024);                                                           // gelu(LN(q)@fc1+b)
    gemm64<0,1,0><<<dim3(4,64), blk, 0, stream>>>(Hb, 1024, WTfc2,
        fc2_b, out, 256, out, 256, 1024);                                           // q += fc2
}

// Round 6
// 277.833 us; speedup vs baseline: 1.4714x; 1.4714x over previous
//
#include <hip/hip_runtime.h>
#include <math.h>

#define NQC   2048
#define NKVC  2048
#define DIMC  256
#define SCALEF 0.17677669529663687f   // 1/sqrt(32), folded into Q weights in prep_w

typedef short bfrag __attribute__((ext_vector_type(8)));   // 8 bf16 = 4 VGPRs
typedef float ffrag __attribute__((ext_vector_type(4)));   // MFMA C/D
typedef unsigned short us8 __attribute__((ext_vector_type(8)));

__device__ __forceinline__ float gelu_exact(float x) {
    return 0.5f * x * (1.0f + erff(x * 0.70710678118654752f));
}
__device__ __forceinline__ unsigned short f2bf(float f) {
    union { float f; unsigned u; } v; v.f = f;
    unsigned r = v.u + 0x7FFFu + ((v.u >> 16) & 1u);   // RNE
    return (unsigned short)(r >> 16);
}
__device__ __forceinline__ float bf2f(unsigned short u) {
    union { unsigned u; float f; } v; v.u = ((unsigned)u) << 16;
    return v.f;
}

// ---------------- weight prep: transpose + cast + concat + knn-diff + Q-scale ----------------
// dst regions (bf16, row-major [N][K]):
//  WT1    [1280][256] @0       : qkv (Q cols pre-scaled) | knn_top | knn_diff
//  WTproj [256][256]  @327680
//  WTmerge[256][512]  @393216
//  WT2    [512][256]  @524288  : ca_q (pre-scaled) | knnx_diff
//  WT3    [768][256]  @655360  : ca_kv(K,V) | knnx_top
//  WTprojx[256][256]  @851968
//  WTmergex[256][512] @917504
//  WTfc1  [1024][256] @1048576
//  WTfc2  [256][1024] @1310720   (total 1572864 ushorts)
__global__ __launch_bounds__(256) void prep_w(
    const float* __restrict__ qkv, const float* __restrict__ knn,
    const float* __restrict__ proj, const float* __restrict__ merge,
    const float* __restrict__ caq, const float* __restrict__ knnx,
    const float* __restrict__ cakv, const float* __restrict__ projx,
    const float* __restrict__ mergex, const float* __restrict__ fc1,
    const float* __restrict__ fc2, unsigned short* __restrict__ dst)
{
    int e = (blockIdx.x * 256 + threadIdx.x) * 4;
    float v[4];
    float scale = 1.0f;
    if (e < 327680) {
        int n = e >> 8, k = e & 255;
        if (n < 768) {
            const float* s = qkv + (size_t)k * 768 + n;
            #pragma unroll
            for (int i = 0; i < 4; ++i) v[i] = s[(size_t)i * 768];
            if (n < 256) scale = SCALEF;            // Q columns: fold attention scale
        } else if (n < 1024) {
            const float* s = knn + (size_t)k * 256 + (n - 768);
            #pragma unroll
            for (int i = 0; i < 4; ++i) v[i] = s[(size_t)i * 256];
        } else {
            const float* s = knn + (size_t)k * 256 + (n - 1024);
            #pragma unroll
            for (int i = 0; i < 4; ++i) v[i] = s[65536 + (size_t)i * 256] - s[(size_t)i * 256];
        }
    } else if (e < 393216) {
        int l = e - 327680, n = l >> 8, k = l & 255;
        const float* s = proj + (size_t)k * 256 + n;
        #pragma unroll
        for (int i = 0; i < 4; ++i) v[i] = s[(size_t)i * 256];
    } else if (e < 524288) {
        int l = e - 393216, n = l >> 9, k = l & 511;
        const float* s = merge + (size_t)k * 256 + n;
        #pragma unroll
        for (int i = 0; i < 4; ++i) v[i] = s[(size_t)i * 256];
    } else if (e < 655360) {
        int l = e - 524288, n = l >> 8, k = l & 255;
        if (n < 256) {
            const float* s = caq + (size_t)k * 256 + n;
            #pragma unroll
            for (int i = 0; i < 4; ++i) v[i] = s[(size_t)i * 256];
            scale = SCALEF;                         // ca_q: fold attention scale
        } else {
            const float* s = knnx + (size_t)k * 256 + (n - 256);
            #pragma unroll
            for (int i = 0; i < 4; ++i) v[i] = s[65536 + (size_t)i * 256] - s[(size_t)i * 256];
        }
    } else if (e < 851968) {
        int l = e - 655360, n = l >> 8, k = l & 255;
        if (n < 512) {
            const float* s = cakv + (size_t)k * 512 + n;
            #pragma unroll
            for (int i = 0; i < 4; ++i) v[i] = s[(size_t)i * 512];
        } else {
            const float* s = knnx + (size_t)k * 256 + (n - 512);
            #pragma unroll
            for (int i = 0; i < 4; ++i) v[i] = s[(size_t)i * 256];
        }
    } else if (e < 917504) {
        int l = e - 851968, n = l >> 8, k = l & 255;
        const float* s = projx + (size_t)k * 256 + n;
        #pragma unroll
        for (int i = 0; i < 4; ++i) v[i] = s[(size_t)i * 256];
    } else if (e < 1048576) {
        int l = e - 917504, n = l >> 9, k = l & 511;
        const float* s = mergex + (size_t)k * 256 + n;
        #pragma unroll
        for (int i = 0; i < 4; ++i) v[i] = s[(size_t)i * 256];
    } else if (e < 1310720) {
        int l = e - 1048576, n = l >> 8, k = l & 255;
        const float* s = fc1 + (size_t)k * 1024 + n;
        #pragma unroll
        for (int i = 0; i < 4; ++i) v[i] = s[(size_t)i * 1024];
    } else {
        int l = e - 1310720, n = l >> 10, k = l & 1023;
        const float* s = fc2 + (size_t)k * 256 + n;
        #pragma unroll
        for (int i = 0; i < 4; ++i) v[i] = s[(size_t)i * 256];
    }
    ushort4 o;
    o.x = f2bf(v[0] * scale); o.y = f2bf(v[1] * scale);
    o.z = f2bf(v[2] * scale); o.w = f2bf(v[3] * scale);
    *(ushort4*)(dst + e) = o;
}

// ---------------- LayerNorm f32 -> bf16: 4 rows/block, one wave per row ----------------
__global__ __launch_bounds__(256) void ln_b(
    const float* __restrict__ x, const float* __restrict__ g,
    const float* __restrict__ b, unsigned short* __restrict__ y)
{
    int wid = threadIdx.x >> 6, lane = threadIdx.x & 63;
    int row = blockIdx.x * 4 + wid;
    const float* xr = x + (size_t)row * DIMC + lane * 4;
    float4 vv = *(const float4*)xr;
    float s  = vv.x + vv.y + vv.z + vv.w;
    float sq = vv.x*vv.x + vv.y*vv.y + vv.z*vv.z + vv.w*vv.w;
    #pragma unroll
    for (int off = 32; off >= 1; off >>= 1) {
        s  += __shfl_xor(s, off);
        sq += __shfl_xor(sq, off);
    }
    float mean = s * (1.0f/DIMC);
    float var  = sq * (1.0f/DIMC) - mean*mean;
    float inv  = rsqrtf(var + 1e-5f);
    float4 gg = *(const float4*)(g + lane*4);
    float4 bb = *(const float4*)(b + lane*4);
    ushort4 o;
    o.x = f2bf((vv.x - mean) * inv * gg.x + bb.x);
    o.y = f2bf((vv.y - mean) * inv * gg.y + bb.y);
    o.z = f2bf((vv.z - mean) * inv * gg.z + bb.z);
    o.w = f2bf((vv.w - mean) * inv * gg.w + bb.w);
    *(ushort4*)(y + (size_t)row * DIMC + lane * 4) = o;
}

// ---------------- bf16 MFMA GEMM, 64x64 tile, BK=64 (bf16 A input) ----------------
template<int ACT, int RESID, int OUTBF>
__global__ __launch_bounds__(256) void gemm64(
    const unsigned short* __restrict__ A, int lda,
    const unsigned short* __restrict__ Wt,
    const float* __restrict__ bias,
    const float* __restrict__ resid, int ldr,
    void* __restrict__ Cp, int ldc, int Kc)
{
    __shared__ unsigned short Alds[64][72];
    __shared__ unsigned short Wlds[64][72];
    const int tid = threadIdx.x;
    const int wid = tid >> 6, lane = tid & 63;
    const int lm = lane & 15, quad = lane >> 4;
    const int wr = wid >> 1, wc = wid & 1;
    const int row0 = blockIdx.y * 64, col0 = blockIdx.x * 64;
    const int ar = tid >> 2, ac = (tid & 3) * 16;
    const unsigned short* Ag = A  + (size_t)(row0 + ar) * lda + ac;
    const unsigned short* Wg = Wt + (size_t)(col0 + ar) * Kc  + ac;

    us8 a0 = *(const us8*)Ag;
    us8 a1 = *(const us8*)(Ag + 8);
    us8 w0 = *(const us8*)Wg;
    us8 w1 = *(const us8*)(Wg + 8);

    ffrag acc[2][2];
    #pragma unroll
    for (int mi = 0; mi < 2; ++mi)
        #pragma unroll
        for (int ni = 0; ni < 2; ++ni)
            acc[mi][ni] = (ffrag){0.f, 0.f, 0.f, 0.f};

    for (int k0 = 0;;) {
        __syncthreads();
        *(us8*)&Alds[ar][ac]   = a0;
        *(us8*)&Alds[ar][ac+8] = a1;
        *(us8*)&Wlds[ar][ac]   = w0;
        *(us8*)&Wlds[ar][ac+8] = w1;
        __syncthreads();
        k0 += 64;
        if (k0 < Kc) {
            a0 = *(const us8*)(Ag + k0);
            a1 = *(const us8*)(Ag + k0 + 8);
            w0 = *(const us8*)(Wg + k0);
            w1 = *(const us8*)(Wg + k0 + 8);
        }
        #pragma unroll
        for (int kc = 0; kc < 2; ++kc) {
            bfrag af[2], bw[2];
            #pragma unroll
            for (int mi = 0; mi < 2; ++mi)
                af[mi] = *(const bfrag*)&Alds[wr*32 + mi*16 + lm][kc*32 + quad*8];
            #pragma unroll
            for (int ni = 0; ni < 2; ++ni)
                bw[ni] = *(const bfrag*)&Wlds[wc*32 + ni*16 + lm][kc*32 + quad*8];
            #pragma unroll
            for (int mi = 0; mi < 2; ++mi)
                #pragma unroll
                for (int ni = 0; ni < 2; ++ni)
                    acc[mi][ni] = __builtin_amdgcn_mfma_f32_16x16x32_bf16(
                        af[mi], bw[ni], acc[mi][ni], 0, 0, 0);
        }
        if (k0 >= Kc) break;
    }
    #pragma unroll
    for (int mi = 0; mi < 2; ++mi) {
        #pragma unroll
        for (int ni = 0; ni < 2; ++ni) {
            int gr = row0 + wr*32 + mi*16 + quad*4;
            int gc = col0 + wc*32 + ni*16 + lm;
            float bv = bias ? bias[gc] : 0.f;
            #pragma unroll
            for (int r = 0; r < 4; ++r) {
                float o = acc[mi][ni][r] + bv;
                if (ACT == 1) o = gelu_exact(o);
                if (RESID) o += resid[(size_t)(gr + r) * ldr + gc];
                if (OUTBF) ((unsigned short*)Cp)[(size_t)(gr + r) * ldc + gc] = f2bf(o);
                else       ((float*)Cp)[(size_t)(gr + r) * ldc + gc] = o;
            }
        }
    }
}

// ---------------- bf16 MFMA flash attention, KV-split, fixed-max softmax ----------------
// grid (NQ/64, 8, B*2): z = b*2 + chunk; each block: 64 queries x 1024 keys.
// Fixed-max partials are exactly additive: Opart(bf16)/Lpart summed in attn_comb.
__global__ __launch_bounds__(256) void attn_part(
    const unsigned short* __restrict__ Qp, int ldq,
    const unsigned short* __restrict__ Kp, int ldk,
    const unsigned short* __restrict__ Vp, int ldv,
    unsigned short* __restrict__ Op, float* __restrict__ Lp)
{
    __shared__ unsigned short Klds[64][40];
    __shared__ unsigned short Vt[32][72];
    __shared__ unsigned short Plds[4][16][72];
    int zc = blockIdx.z, bb = zc >> 1, ck = zc & 1;
    int h = blockIdx.y;
    int hoff = h * 32;
    int tid = threadIdx.x, wid = tid >> 6, lane = tid & 63;
    int lm = lane & 15, quad = lane >> 4;
    size_t qbase  = (size_t)bb * NQC;
    size_t kvbase = (size_t)bb * NKVC;
    int q0 = blockIdx.x * 64 + wid * 16;

    bfrag aq = *(const bfrag*)(Qp + (qbase + q0 + lm) * (size_t)ldq + hoff + quad * 8);

    float l_r[4] = {0.f, 0.f, 0.f, 0.f};
    ffrag oacc[2];
    oacc[0] = (ffrag){0.f, 0.f, 0.f, 0.f};
    oacc[1] = (ffrag){0.f, 0.f, 0.f, 0.f};

    const int kkey = tid >> 2, kd0 = (tid & 3) * 8;
    const int vkey = tid & 63, vd0 = (tid >> 6) * 8;
    const unsigned short* kg0 = Kp + (kvbase + kkey) * (size_t)ldk + hoff + kd0;
    const unsigned short* vg0 = Vp + (kvbase + vkey) * (size_t)ldv + hoff + vd0;

    for (int kt = ck * 16; kt < ck * 16 + 16; ++kt) {
        us8 kv = *(const us8*)(kg0 + (size_t)kt * 64 * ldk);
        us8 vv = *(const us8*)(vg0 + (size_t)kt * 64 * ldv);
        __syncthreads();
        *(us8*)&Klds[kkey][kd0] = kv;
        #pragma unroll
        for (int i = 0; i < 8; ++i) Vt[vd0 + i][vkey] = vv[i];
        __syncthreads();

        ffrag sacc[4];
        #pragma unroll
        for (int t = 0; t < 4; ++t) {
            bfrag bk = *(const bfrag*)&Klds[t*16 + lm][quad * 8];
            sacc[t] = __builtin_amdgcn_mfma_f32_16x16x32_bf16(
                aq, bk, (ffrag){0.f,0.f,0.f,0.f}, 0, 0, 0);
        }

        #pragma unroll
        for (int r = 0; r < 4; ++r) {
            float p0 = __expf(sacc[0][r]), p1 = __expf(sacc[1][r]);
            float p2 = __expf(sacc[2][r]), p3 = __expf(sacc[3][r]);
            l_r[r] += (p0 + p1) + (p2 + p3);
            int row = quad * 4 + r;
            Plds[wid][row][lm +  0] = f2bf(p0);
            Plds[wid][row][lm + 16] = f2bf(p1);
            Plds[wid][row][lm + 32] = f2bf(p2);
            Plds[wid][row][lm + 48] = f2bf(p3);
        }
        asm volatile("s_waitcnt lgkmcnt(0)" ::: "memory");  // wave-private P RAW

        #pragma unroll
        for (int kc = 0; kc < 2; ++kc) {
            bfrag ap = *(const bfrag*)&Plds[wid][lm][kc*32 + quad*8];
            #pragma unroll
            for (int nt = 0; nt < 2; ++nt) {
                bfrag bv = *(const bfrag*)&Vt[nt*16 + lm][kc*32 + quad*8];
                oacc[nt] = __builtin_amdgcn_mfma_f32_16x16x32_bf16(
                    ap, bv, oacc[nt], 0, 0, 0);
            }
        }
    }
    // partial O (bf16) + partial l (f32); division deferred to attn_comb
    #pragma unroll
    for (int nt = 0; nt < 2; ++nt)
        #pragma unroll
        for (int r = 0; r < 4; ++r)
            Op[((size_t)ck * 4096 + qbase + q0 + quad*4 + r) * 256 + hoff + nt*16 + lm]
                = f2bf(oacc[nt][r]);
    #pragma unroll
    for (int r = 0; r < 4; ++r) {
        float l = l_r[r];
        l += __shfl_xor(l, 1);
        l += __shfl_xor(l, 2);
        l += __shfl_xor(l, 4);
        l += __shfl_xor(l, 8);
        if (lm == 0)
            Lp[((size_t)ck * 4096 + qbase + q0 + quad*4 + r) * 8 + h] = l;
    }
}

// ---------------- combine KV-split partials: (O0+O1)/(l0+l1) -> bf16 ----------------
__global__ __launch_bounds__(256) void attn_comb(
    const unsigned short* __restrict__ Op, const float* __restrict__ Lp,
    unsigned short* __restrict__ dst)
{
    int wid = threadIdx.x >> 6, lane = threadIdx.x & 63;
    int row = blockIdx.x * 4 + wid;
    int c = lane * 4, h = c >> 5;
    ushort4 o0 = *(const ushort4*)(Op + (size_t)row * 256 + c);
    ushort4 o1 = *(const ushort4*)(Op + (size_t)(4096 + row) * 256 + c);
    float inv = 1.0f / (Lp[(size_t)row * 8 + h] + Lp[(size_t)(4096 + row) * 8 + h]);
    ushort4 o;
    o.x = f2bf((bf2f(o0.x) + bf2f(o1.x)) * inv);
    o.y = f2bf((bf2f(o0.y) + bf2f(o1.y)) * inv);
    o.z = f2bf((bf2f(o0.z) + bf2f(o1.z)) * inv);
    o.w = f2bf((bf2f(o0.w) + bf2f(o1.w)) * inv);
    *(ushort4*)(dst + (size_t)row * 256 + c) = o;
}

// ---------------- KNN gather + leaky_relu + max over K=8 (bf16 io) ----------------
__global__ __launch_bounds__(256) void gathermax_b(
    const unsigned short* __restrict__ P, int ldp,
    const unsigned short* __restrict__ Base, int ldb,
    const float* __restrict__ bias, const int* __restrict__ idx,
    unsigned short* __restrict__ out, int ldo)
{
    int wid = threadIdx.x >> 6, lane = threadIdx.x & 63;
    int q = blockIdx.x * 4 + wid;
    int b = q >> 11;
    int c = lane * 4;
    ushort4 bu = *(const ushort4*)(Base + (size_t)q * ldb + c);
    float4 bi = *(const float4*)(bias + c);
    float bsx = bf2f(bu.x) + bi.x, bsy = bf2f(bu.y) + bi.y;
    float bsz = bf2f(bu.z) + bi.z, bsw = bf2f(bu.w) + bi.w;
    float4 acc = make_float4(-3e38f, -3e38f, -3e38f, -3e38f);
    const int* ip = idx + (size_t)q * 8;
    #pragma unroll
    for (int k = 0; k < 8; ++k) {
        int j = ip[k];
        ushort4 pu = *(const ushort4*)(P + ((size_t)(b * NKVC + j)) * ldp + c);
        float t;
        t = bsx + bf2f(pu.x); t = t > 0.f ? t : 0.2f * t; acc.x = fmaxf(acc.x, t);
        t = bsy + bf2f(pu.y); t = t > 0.f ? t : 0.2f * t; acc.y = fmaxf(acc.y, t);
        t = bsz + bf2f(pu.z); t = t > 0.f ? t : 0.2f * t; acc.z = fmaxf(acc.z, t);
        t = bsw + bf2f(pu.w); t = t > 0.f ? t : 0.2f * t; acc.w = fmaxf(acc.w, t);
    }
    ushort4 o;
    o.x = f2bf(acc.x); o.y = f2bf(acc.y); o.z = f2bf(acc.z); o.w = f2bf(acc.w);
    *(ushort4*)(out + (size_t)q * ldo + c) = o;
}

extern "C" void kernel_launch(void* const* d_in, const int* in_sizes, int n_in,
                              void* d_out, int out_size, void* d_ws, size_t ws_size,
                              hipStream_t stream) {
    const float* q_in   = (const float*)d_in[0];
    const float* v_in   = (const float*)d_in[1];
    const int*   idx_s  = (const int*)d_in[4];
    const int*   idx_x  = (const int*)d_in[5];
    const float* n1g = (const float*)d_in[6],  *n1b = (const float*)d_in[7];
    const float* nqg = (const float*)d_in[8],  *nqb = (const float*)d_in[9];
    const float* nvg = (const float*)d_in[10], *nvb = (const float*)d_in[11];
    const float* n2g = (const float*)d_in[12], *n2b = (const float*)d_in[13];
    const float* sa_qkv_w  = (const float*)d_in[14];
    const float* sa_proj_w = (const float*)d_in[15];
    const float* sa_proj_b = (const float*)d_in[16];
    const float* ca_q_w    = (const float*)d_in[17];
    const float* ca_kv_w   = (const float*)d_in[18];
    const float* ca_proj_w = (const float*)d_in[19];
    const float* ca_proj_b = (const float*)d_in[20];
    const float* fc1_w = (const float*)d_in[21], *fc1_b = (const float*)d_in[22];
    const float* fc2_w = (const float*)d_in[23], *fc2_b = (const float*)d_in[24];
    const float* knn_w   = (const float*)d_in[25], *knn_b   = (const float*)d_in[26];
    const float* merge_w = (const float*)d_in[27], *merge_b = (const float*)d_in[28];
    const float* knnx_w  = (const float*)d_in[29], *knnx_b  = (const float*)d_in[30];
    const float* mergex_w = (const float*)d_in[31], *mergex_b = (const float*)d_in[32];
    float* out = (float*)d_out;

    unsigned short* A1      = (unsigned short*)d_ws;           // 4096x1280 bf16
    unsigned short* A2      = A1;                              // 4096x512 (stage2 overlay)
    unsigned short* A3      = A1 + (size_t)4096 * 512;         // 4096x768 (stage2 overlay)
    unsigned short* Hb      = A1;                              // 4096x1024 (stage3 overlay)
    unsigned short* attnraw = A1 + (size_t)4096 * 1280;        // 4096x256
    unsigned short* CC      = attnraw + (size_t)4096 * 256;    // 4096x512 concat
    unsigned short* XB      = CC + (size_t)4096 * 512;         // 4096x256 LN out (nq/nq2/h)
    unsigned short* NVB     = XB + (size_t)4096 * 256;         // 4096x256 LN(v)
    unsigned short* WT      = NVB + (size_t)4096 * 256;        // weights, 1572864 us
    unsigned short* WT1     = WT;
    unsigned short* WTproj  = WT + 327680;
    unsigned short* WTmerge = WT + 393216;
    unsigned short* WT2     = WT + 524288;
    unsigned short* WT3     = WT + 655360;
    unsigned short* WTprojx = WT + 851968;
    unsigned short* WTmergex= WT + 917504;
    unsigned short* WTfc1   = WT + 1048576;
    unsigned short* WTfc2   = WT + 1310720;
    unsigned short* Opart   = WT + 1572864;                    // [2][4096][256] bf16
    float* Lpart = (float*)(Opart + (size_t)2 * 4096 * 256);   // [2][4096][8]  f32

    dim3 blk(256);
    dim3 gAttn(NQC / 64, 8, 4);   // z = b*2 + kv-chunk

    prep_w<<<dim3(1536), blk, 0, stream>>>(sa_qkv_w, knn_w, sa_proj_w, merge_w,
        ca_q_w, knnx_w, ca_kv_w, ca_proj_w, mergex_w, fc1_w, fc2_w, WT);

    // ---- stage 1 ----
    ln_b<<<dim3(1024), blk, 0, stream>>>(q_in, n1g, n1b, XB);                       // nq
    gemm64<0,0,1><<<dim3(20,64), blk, 0, stream>>>(XB, 256, WT1,
        nullptr, nullptr, 0, A1, 1280, 256);                                        // [qkv|P|Base]
    attn_part<<<gAttn, blk, 0, stream>>>(A1, 1280, A1+256, 1280, A1+512, 1280,
        Opart, Lpart);
    attn_comb<<<dim3(1024), blk, 0, stream>>>(Opart, Lpart, attnraw);
    gathermax_b<<<dim3(1024), blk, 0, stream>>>(A1+768, 1280, A1+1024, 1280,
        knn_b, idx_s, CC+256, 512);                                                 // knn_out
    gemm64<0,0,1><<<dim3(4,64), blk, 0, stream>>>(attnraw, 256, WTproj,
        sa_proj_b, nullptr, 0, CC, 512, 256);                                       // sa_out
    gemm64<0,1,0><<<dim3(4,64), blk, 0, stream>>>(CC, 512, WTmerge,
        merge_b, q_in, 256, out, 256, 512);                                         // q = q + merge

    // ---- stage 2 ----
    ln_b<<<dim3(1024), blk, 0, stream>>>(out, nqg, nqb, XB);                        // nq2
    ln_b<<<dim3(1024), blk, 0, stream>>>(v_in, nvg, nvb, NVB);                      // nv
    gemm64<0,0,1><<<dim3(8,64), blk, 0, stream>>>(XB, 256, WT2,
        nullptr, nullptr, 0, A2, 512, 256);                                         // [ca_q|Base_x]
    gemm64<0,0,1><<<dim3(12,64), blk, 0, stream>>>(NVB, 256, WT3,
        nullptr, nullptr, 0, A3, 768, 256);                                         // [ca_k|ca_v|P_x]
    attn_part<<<gAttn, blk, 0, stream>>>(A2, 512, A3, 768, A3+256, 768,
        Opart, Lpart);
    attn_comb<<<dim3(1024), blk, 0, stream>>>(Opart, Lpart, attnraw);
    gathermax_b<<<dim3(1024), blk, 0, stream>>>(A3+512, 768, A2+256, 512,
        knnx_b, idx_x, CC+256, 512);                                                // knnx_out
    gemm64<0,0,1><<<dim3(4,64), blk, 0, stream>>>(attnraw, 256, WTprojx,
        ca_proj_b, nullptr, 0, CC, 512, 256);                                       // ca_out
    gemm64<0,1,0><<<dim3(4,64), blk, 0, stream>>>(CC, 512, WTmergex,
        mergex_b, out, 256, out, 256, 512);                                         // q = q + mergex

    // ---- stage 3 ----
    ln_b<<<dim3(1024), blk, 0, stream>>>(out, n2g, n2b, XB);                        // h = LN(q)
    gemm64<1,0,1><<<dim3(16,64), blk, 0, stream>>>(XB, 256, WTfc1,
        fc1_b, nullptr, 0, Hb, 1024, 256);                                          // gelu(LN(q)@fc1+b)
    gemm64<0,1,0><<<dim3(4,64), blk, 0, stream>>>(Hb, 1024, WTfc2,
        fc2_b, out, 256, out, 256, 1024);                                           // q += fc2
}